// Round 13
// baseline (959.695 us; speedup 1.0000x reference)
//
#include <hip/hip_runtime.h>
#include <math.h>

typedef unsigned short u16;
typedef __attribute__((ext_vector_type(8))) short short8;
typedef __attribute__((ext_vector_type(4))) short short4v;
typedef __attribute__((ext_vector_type(4))) float floatx4;

__device__ __forceinline__ float bf2f(u16 u) {
  union { unsigned int i; float f; } v; v.i = ((unsigned int)u) << 16; return v.f;
}
__device__ __forceinline__ u16 f2bf(float f) {
  union { unsigned int i; float f; } v; v.f = f;
  unsigned int i = v.i;
  unsigned int lsb = (i >> 16) & 1u;
  i += 0x7fffu + lsb;          // round-to-nearest-even
  return (u16)(i >> 16);
}

// ---------------------------------------------------------------------------
// Fused front GEMM (R12 swapped-operand form + setprio).
// ---------------------------------------------------------------------------
__global__ __launch_bounds__(256, 2)
void fused_front_k(const float* __restrict__ edge, const u16* __restrict__ Wcomb,
                   const float* __restrict__ b_er, const float* __restrict__ cmb,
                   u16* __restrict__ es, u16* __restrict__ Em)
{
  __shared__ __align__(16) u16 As[64 * 232];
  const int tid  = threadIdx.x;
  const int lane = tid & 63;
  const int wv   = tid >> 6;
  const int q    = lane >> 4;
  const int cl   = lane & 15;
  const long r0  = (long)blockIdx.x * 64;

  for (int z = tid; z < 64 * 24; z += 256) {
    const int zr = z / 24;
    As[zr * 232 + 200 + (z - zr * 24)] = 0;
  }
  const float4* src = (const float4*)(edge + r0 * 200);
  for (int it = tid; it < 3200; it += 256) {
    const float4 v = src[it];
    const int row = it / 50;
    const int c4  = it - row * 50;
    u16 t[4] = { f2bf(v.x), f2bf(v.y), f2bf(v.z), f2bf(v.w) };
    *(short4v*)&As[row * 232 + c4 * 4] = *(short4v*)t;
  }
  __syncthreads();

  floatx4 acc[8][4];   // [wtile over 128 out-cols][rtile over 64 rows]
#pragma unroll
  for (int wi = 0; wi < 8; ++wi)
#pragma unroll
    for (int ri = 0; ri < 4; ++ri)
      acc[wi][ri] = (floatx4){0.f, 0.f, 0.f, 0.f};

  short8 b0[8], b1[8];
#pragma unroll
  for (int wi = 0; wi < 8; ++wi)
    b0[wi] = *(const short8*)(Wcomb + (long)(wv * 128 + wi * 16 + cl) * 224 + q * 8);
#pragma unroll
  for (int ks = 0; ks < 7; ++ks) {
    short8* bc = (ks & 1) ? b1 : b0;
    short8* bn = (ks & 1) ? b0 : b1;
    if (ks < 6) {
      const int kb = (ks + 1) * 32;
#pragma unroll
      for (int wi = 0; wi < 8; ++wi)
        bn[wi] = *(const short8*)(Wcomb + (long)(wv * 128 + wi * 16 + cl) * 224 + kb + q * 8);
    }
    short8 a[4];
#pragma unroll
    for (int ri = 0; ri < 4; ++ri)
      a[ri] = *(const short8*)&As[(ri * 16 + cl) * 232 + ks * 32 + q * 8];
    __builtin_amdgcn_s_setprio(1);
#pragma unroll
    for (int wi = 0; wi < 8; ++wi)
#pragma unroll
      for (int ri = 0; ri < 4; ++ri)
        acc[wi][ri] = __builtin_amdgcn_mfma_f32_16x16x32_bf16(bc[wi], a[ri], acc[wi][ri], 0, 0, 0);
    __builtin_amdgcn_s_setprio(0);
  }

  const bool is_ef   = (wv < 2);
  const float* bias  = is_ef ? b_er : cmb;
  u16* dst           = is_ef ? es : Em;
  const int colbase  = (wv & 1) * 128;
#pragma unroll
  for (int wi = 0; wi < 8; ++wi) {
    const int c0i = colbase + wi * 16 + q * 4;    // 4 consecutive out-cols
    const float4 bv = *(const float4*)&bias[c0i];
    const float bb[4] = {bv.x, bv.y, bv.z, bv.w};
#pragma unroll
    for (int ri = 0; ri < 4; ++ri) {
      const int row = ri * 16 + cl;
      u16 p[4];
#pragma unroll
      for (int r = 0; r < 4; ++r)
        p[r] = f2bf(acc[wi][ri][r] + bb[r]);
      *(short4v*)&dst[(r0 + row) * 256 + c0i] = *(short4v*)p;
    }
  }
}

// ---------------------------------------------------------------------------
// linkmsg: link MLP + message + aggregation + GRU, one dispatch/iteration.
// R17: block bid owns node-row bid; after the msum reduction the full msum
// row is in LDS, so gi = msum @ W_ih^T is a per-block fp32 matvec against
// pre-transposed WihT (coalesced float2, L2-resident 786 KB) and the GRU
// update is row-local. Removes the gemm_gru dispatch (x3), the msum hi/lo
// round-trip, and the Wih split. gi is now EXACT fp32 (more accurate than
// the old split-MFMA path); association (gi + b_ih) + gh preserved.
// ---------------------------------------------------------------------------
__global__ __launch_bounds__(512, 2)
void linkmsg_k(const u16* __restrict__ es, const u16* __restrict__ Wl1b,
               const float* __restrict__ bl1, const u16* __restrict__ Wl2b,
               const float* __restrict__ bl2, const float* __restrict__ wl3,
               const float* __restrict__ bl3, const u16* __restrict__ Em,
               const float* __restrict__ Hm, float* __restrict__ adj,
               u16* __restrict__ esn,
               const float* __restrict__ WihT,   // [256 x 768] fp32
               const float* __restrict__ b_ih,
               const float* __restrict__ gh,     // [1024 x 768] (incl b_hh)
               float* __restrict__ h,            // [1024 x 256] fp32 in/out
               u16* __restrict__ h_h, u16* __restrict__ h_l,
               const int write_adj, const int write_es)
{
  __shared__ __align__(16) u16 x1b[128 * 512];   // 128 KB; [0,64K) doubles as es tile
  const int tid  = threadIdx.x;
  const int lane = tid & 63;
  const int wv   = tid >> 6;        // wave 0..7 -> 64-out-col slice
  const int q    = lane >> 4;
  const int cl   = lane & 15;
  const int nw0  = wv * 64;
  const long r0  = (long)blockIdx.x * 128;

  // ---- stage es tile [128 x 256 bf16] = 64 KB into LDS, swizzled ----
  {
    const short8* gsrc = (const short8*)(es + r0 * 256);   // 4096 16B-chunks
#pragma unroll
    for (int i = 0; i < 8; ++i) {
      const int g   = tid + i * 512;
      const int row = g >> 5;          // 32 chunks per row
      const int c   = g & 31;
      const short8 v = gsrc[g];
      *(short8*)&x1b[row * 256 + ((c ^ (row & 15)) << 3)] = v;
    }
  }

  floatx4 acc[4][8];   // [wtile over 64 out-cols][rtile over 128 rows]
#pragma unroll
  for (int ni = 0; ni < 4; ++ni)
#pragma unroll
    for (int mi = 0; mi < 8; ++mi)
      acc[ni][mi] = (floatx4){0.f, 0.f, 0.f, 0.f};

  // first weight fragments can load while staging completes
  short8 b0[4], b1[4];
#pragma unroll
  for (int ni = 0; ni < 4; ++ni)
    b0[ni] = *(const short8*)(Wl1b + (nw0 + ni * 16 + cl) * 256 + q * 8);
  __syncthreads();

  // ---------------- phase 1: x1^T = Wl1 @ es^T (swapped operands) --------
  {
#pragma unroll
    for (int ks = 0; ks < 8; ++ks) {
      short8* bc = (ks & 1) ? b1 : b0;
      short8* bn = (ks & 1) ? b0 : b1;
      if (ks < 7) {
        const int kb = (ks + 1) * 32;
#pragma unroll
        for (int ni = 0; ni < 4; ++ni)
          bn[ni] = *(const short8*)(Wl1b + (nw0 + ni * 16 + cl) * 256 + kb + q * 8);
      }
      short8 a[8];
#pragma unroll
      for (int mi = 0; mi < 8; ++mi) {
        const int row = mi * 16 + cl;
        a[mi] = *(const short8*)&x1b[row * 256 + (((ks * 4 + q) ^ cl) << 3)];
      }
      __builtin_amdgcn_s_setprio(1);
#pragma unroll
      for (int ni = 0; ni < 4; ++ni)
#pragma unroll
        for (int mi = 0; mi < 8; ++mi)
          acc[ni][mi] = __builtin_amdgcn_mfma_f32_16x16x32_bf16(bc[ni], a[mi], acc[ni][mi], 0, 0, 0);
      __builtin_amdgcn_s_setprio(0);
    }
  }
  __syncthreads();   // all waves done READING the es tile before x1 overwrites it

  // epilogue 1: packed b64 x1 writes. Lane's 4 acc values = out-cols
  // ocb..ocb+3 of row (mi*16+cl); all 4 stay in one swizzle chunk.
  {
#pragma unroll
    for (int ni = 0; ni < 4; ++ni) {
      const int ocb   = nw0 + ni * 16 + q * 4;
      const float4 bv = *(const float4*)&bl1[ocb];
      const float bb[4] = {bv.x, bv.y, bv.z, bv.w};
      const int chunk = ocb >> 3;
      const int off   = ocb & 7;
#pragma unroll
      for (int mi = 0; mi < 8; ++mi) {
        const int row = mi * 16 + cl;          // row&15 == cl
        u16 p[4];
#pragma unroll
        for (int r = 0; r < 4; ++r)
          p[r] = f2bf(fmaxf(acc[ni][mi][r] + bb[r], 0.f));
        *(short4v*)&x1b[row * 512 + ((chunk ^ cl) << 3) + off] = *(short4v*)p;
      }
    }
  }
#pragma unroll
  for (int ni = 0; ni < 4; ++ni)
#pragma unroll
    for (int mi = 0; mi < 8; ++mi)
      acc[ni][mi] = (floatx4){0.f, 0.f, 0.f, 0.f};
  __syncthreads();

  // ---------------- phase 2: D^T = Wl2 @ x1^T (swapped operands) ---------
  {
    short8 c0[4], c1[4];
#pragma unroll
    for (int ni = 0; ni < 4; ++ni)
      c0[ni] = *(const short8*)(Wl2b + (nw0 + ni * 16 + cl) * 512 + q * 8);
#pragma unroll
    for (int ks = 0; ks < 16; ++ks) {
      short8* cc = (ks & 1) ? c1 : c0;
      short8* cn = (ks & 1) ? c0 : c1;
      if (ks < 15) {
        const int kb = (ks + 1) * 32;
#pragma unroll
        for (int ni = 0; ni < 4; ++ni)
          cn[ni] = *(const short8*)(Wl2b + (nw0 + ni * 16 + cl) * 512 + kb + q * 8);
      }
      short8 a[8];
#pragma unroll
      for (int mi = 0; mi < 8; ++mi) {
        const int row = mi * 16 + cl;
        a[mi] = *(const short8*)&x1b[row * 512 + (((ks * 4 + q) ^ cl) << 3)];
      }
      __builtin_amdgcn_s_setprio(1);
#pragma unroll
      for (int ni = 0; ni < 4; ++ni)
#pragma unroll
        for (int mi = 0; mi < 8; ++mi)
          acc[ni][mi] = __builtin_amdgcn_mfma_f32_16x16x32_bf16(cc[ni], a[mi], acc[ni][mi], 0, 0, 0);
      __builtin_amdgcn_s_setprio(0);
    }
  }

  // epilogue 2: relu(+bl2), dot wl3. Lane holds 16 out-cols of row
  // (mi*16+cl) -> serial 16-term sums, then 2-level shuffle over q only.
  float pv[8];
#pragma unroll
  for (int mi = 0; mi < 8; ++mi) pv[mi] = 0.f;
#pragma unroll
  for (int ni = 0; ni < 4; ++ni) {
    const int ocb   = nw0 + ni * 16 + q * 4;
    const float4 b2 = *(const float4*)&bl2[ocb];
    const float4 w3 = *(const float4*)&wl3[ocb];
    const float bb[4] = {b2.x, b2.y, b2.z, b2.w};
    const float ww[4] = {w3.x, w3.y, w3.z, w3.w};
#pragma unroll
    for (int mi = 0; mi < 8; ++mi) {
#pragma unroll
      for (int r = 0; r < 4; ++r)
        pv[mi] += fmaxf(acc[ni][mi][r] + bb[r], 0.f) * ww[r];
    }
  }
  __syncthreads();                    // all x1b reads done; reuse as scratch
  float* pf   = (float*)x1b;          // [8 waves][128 rows]  (4 KB)
  float* sigv = pf + 1024;            // 128 floats
  float* red  = pf + 2048;            // 4096 floats  (pf+2048 .. pf+6144)
  float* msv  = pf + 6144;            // 256 floats
  float* giL  = pf + 6464;            // 768 floats
#pragma unroll
  for (int mi = 0; mi < 8; ++mi) {
    float p = pv[mi];
    p += __shfl_xor(p, 16, 64);
    p += __shfl_xor(p, 32, 64);
    if (q == 0) pf[wv * 128 + mi * 16 + cl] = p;
  }
  __syncthreads();
  if (tid < 128) {
    float s = bl3[0];
#pragma unroll
    for (int w = 0; w < 8; ++w) s += pf[w * 128 + tid];
    if (write_adj) adj[r0 + tid] = s;
    sigv[tid] = 1.f / (1.f + __expf(-s));
  }
  __syncthreads();

  // ---------------- message tail: M = relu(Em + Hm)*sig; scatter + sum ----
  const int b  = (int)(blockIdx.x >> 7);
  const int i  = (int)(blockIdx.x & 127);
  const int g  = tid >> 5;          // stripe 0..15
  const int c8 = (tid & 31) * 8;    // col block
  float msacc[8] = {0.f, 0.f, 0.f, 0.f, 0.f, 0.f, 0.f, 0.f};
  for (int w0 = 0; w0 < 128; w0 += 16) {
    const int w = w0 + g;
    const float s = sigv[w];
    const short8 ev = *(const short8*)(Em + (r0 + w) * 256 + c8);
    const float4 h0 = *(const float4*)(Hm + ((long)(b * 128 + w)) * 256 + c8);
    const float4 h1 = *(const float4*)(Hm + ((long)(b * 128 + w)) * 256 + c8 + 4);
    const float hv[8] = {h0.x, h0.y, h0.z, h0.w, h1.x, h1.y, h1.z, h1.w};
    u16 mb[8];
#pragma unroll
    for (int j = 0; j < 8; ++j) {
      float x = fmaxf(bf2f(((const u16*)&ev)[j]) + hv[j], 0.f) * s;
      msacc[j] += x;
      mb[j] = f2bf(x);
    }
    if (write_es)
      *(short8*)(esn + (((long)(b * 128 + w)) * 128 + i) * 256 + c8) = *(short8*)mb;
  }
  // red[tid*8 + j] holds col ((tid&31)*8+j) of stripe (tid>>5);
  // reader index for col t, stripe g is red[g*256 + t] (stride-1 reads).
  {
    float4 m0 = {msacc[0], msacc[1], msacc[2], msacc[3]};
    float4 m1 = {msacc[4], msacc[5], msacc[6], msacc[7]};
    *(float4*)&red[tid * 8]     = m0;
    *(float4*)&red[tid * 8 + 4] = m1;
  }
  __syncthreads();
  if (tid < 256) {
    float s = 0.f;
#pragma unroll
    for (int gg = 0; gg < 16; ++gg) s += red[gg * 256 + tid];
    msv[tid] = s;             // full msum row for node `blockIdx.x`, in LDS
  }
  __syncthreads();

  // ---------------- gi matvec + GRU (row-local) ----------------
  // gi[o] = sum_k msv[k] * W_ih[o][k]  == msv . WihT[:,o]  (exact fp32)
  if (tid < 384) {
    const int o2 = tid * 2;
    float ax = 0.f, ay = 0.f;
#pragma unroll 4
    for (int k = 0; k < 256; ++k) {
      const float m = msv[k];
      const float2 w2 = *(const float2*)&WihT[k * 768 + o2];
      ax += m * w2.x;
      ay += m * w2.y;
    }
    giL[o2]     = ax;
    giL[o2 + 1] = ay;
  }
  __syncthreads();
  if (tid < 256) {
    const int row = (int)blockIdx.x;       // b*128 + i
    const long gb = (long)row * 768;
    const float gr = (giL[tid]       + b_ih[tid])       + gh[gb + tid];
    const float gz = (giL[256 + tid] + b_ih[256 + tid]) + gh[gb + 256 + tid];
    const float rv = 1.f / (1.f + __expf(-gr));
    const float zv = 1.f / (1.f + __expf(-gz));
    const float nv = tanhf((giL[512 + tid] + b_ih[512 + tid]) + rv * gh[gb + 512 + tid]);
    const int hidx = row * 256 + tid;
    const float hv = (1.f - zv) * nv + zv * h[hidx];
    h[hidx] = hv;
    const u16 hh = f2bf(hv);
    h_h[hidx] = hh;
    h_l[hidx] = f2bf(hv - bf2f(hh));
  }
}

// ---------------------------------------------------------------------------
// Pre-split GEMM (~fp32 accuracy), 128x128 tiles — used for h0 and labels.
// ---------------------------------------------------------------------------
__device__ __forceinline__
void gemm_ps_dev(const u16* __restrict__ Ah, const u16* __restrict__ Al,
                 const u16* __restrict__ Bh, const u16* __restrict__ Bl,
                 const float* __restrict__ bias,
                 float* __restrict__ C, u16* __restrict__ Ch, u16* __restrict__ Cl,
                 int N, int K, int lda, int ldc, int bx, int by)
{
  __shared__ __align__(16) u16 Ash[128 * 40];
  __shared__ __align__(16) u16 Asl[128 * 40];
  __shared__ __align__(16) u16 Bsh[128 * 40];
  __shared__ __align__(16) u16 Bsl[128 * 40];
  const int tid  = threadIdx.x;
  const int m0   = bx * 128;
  const int n0   = by * 128;
  const int lane = tid & 63;
  const int wv   = tid >> 6;
  const int wm   = wv & 1;
  const int wn   = wv >> 1;
  const int q    = lane >> 4;
  const int cl   = lane & 15;

  floatx4 acc[4][4];
#pragma unroll
  for (int i = 0; i < 4; ++i)
#pragma unroll
    for (int j = 0; j < 4; ++j)
      acc[i][j] = (floatx4){0.f, 0.f, 0.f, 0.f};

  const int srow = tid >> 1;
  const int scol = (tid & 1) * 16;

  for (int kb = 0; kb < K; kb += 32) {
    {
      const long ar = (long)(m0 + srow) * lda + kb + scol;
      *(short8*)&Ash[srow * 40 + scol]     = *(const short8*)(Ah + ar);
      *(short8*)&Ash[srow * 40 + scol + 8] = *(const short8*)(Ah + ar + 8);
      *(short8*)&Asl[srow * 40 + scol]     = *(const short8*)(Al + ar);
      *(short8*)&Asl[srow * 40 + scol + 8] = *(const short8*)(Al + ar + 8);
    }
    {
      const int n = n0 + srow;
      u16* dh = &Bsh[srow * 40 + scol];
      u16* dl = &Bsl[srow * 40 + scol];
      if (n < N) {
        const long br = (long)n * K + kb + scol;
        ((short8*)dh)[0] = *(const short8*)(Bh + br);
        ((short8*)dh)[1] = *(const short8*)(Bh + br + 8);
        ((short8*)dl)[0] = *(const short8*)(Bl + br);
        ((short8*)dl)[1] = *(const short8*)(Bl + br + 8);
      } else {
#pragma unroll
        for (int j = 0; j < 16; ++j) { dh[j] = 0; dl[j] = 0; }
      }
    }
    __syncthreads();

    short8 ah[4], al[4], bh[4], bl[4];
#pragma unroll
    for (int mi = 0; mi < 4; ++mi) {
      ah[mi] = *(const short8*)&Ash[(wm * 64 + mi * 16 + cl) * 40 + q * 8];
      al[mi] = *(const short8*)&Asl[(wm * 64 + mi * 16 + cl) * 40 + q * 8];
    }
#pragma unroll
    for (int ni = 0; ni < 4; ++ni) {
      bh[ni] = *(const short8*)&Bsh[(wn * 64 + ni * 16 + cl) * 40 + q * 8];
      bl[ni] = *(const short8*)&Bsl[(wn * 64 + ni * 16 + cl) * 40 + q * 8];
    }
#pragma unroll
    for (int mi = 0; mi < 4; ++mi)
#pragma unroll
      for (int ni = 0; ni < 4; ++ni) {
        acc[mi][ni] = __builtin_amdgcn_mfma_f32_16x16x32_bf16(ah[mi], bh[ni], acc[mi][ni], 0, 0, 0);
        acc[mi][ni] = __builtin_amdgcn_mfma_f32_16x16x32_bf16(al[mi], bh[ni], acc[mi][ni], 0, 0, 0);
        acc[mi][ni] = __builtin_amdgcn_mfma_f32_16x16x32_bf16(ah[mi], bl[ni], acc[mi][ni], 0, 0, 0);
      }
    __syncthreads();
  }

#pragma unroll
  for (int mi = 0; mi < 4; ++mi) {
    const int row = m0 + wm * 64 + mi * 16 + q * 4;
#pragma unroll
    for (int ni = 0; ni < 4; ++ni) {
      const int col = n0 + wn * 64 + ni * 16 + cl;
      if (col < N) {
        const float b = bias ? bias[col] : 0.f;
#pragma unroll
        for (int r = 0; r < 4; ++r) {
          float v = acc[mi][ni][r] + b;
          const long o = (long)(row + r) * ldc + col;
          C[o] = v;
          if (Ch) {
            const u16 hi = f2bf(v);
            Ch[o] = hi;
            Cl[o] = f2bf(v - bf2f(hi));
          }
        }
      }
    }
  }
}

__global__ __launch_bounds__(256, 2)
void gemm_ps_k(const u16* __restrict__ Ah, const u16* __restrict__ Al,
               const u16* __restrict__ Bh, const u16* __restrict__ Bl,
               const float* __restrict__ bias,
               float* __restrict__ C, u16* __restrict__ Ch, u16* __restrict__ Cl,
               int N, int K, int lda, int ldc)
{
  gemm_ps_dev(Ah, Al, Bh, Bl, bias, C, Ch, Cl, N, K, lda, ldc,
              blockIdx.x, blockIdx.y);
}

// Hm/gh GEMM, 64x64 tiles, grid (16,16) = 256 blocks (R16 form).
__global__ __launch_bounds__(256, 2)
void gemm_hm_gh_k(const u16* __restrict__ h_h, const u16* __restrict__ h_l,
                  const u16* __restrict__ Wmh_h, const u16* __restrict__ Wmh_l,
                  const u16* __restrict__ Whh_h, const u16* __restrict__ Whh_l,
                  const float* __restrict__ b_hh,
                  float* __restrict__ Hm, float* __restrict__ gh)
{
  __shared__ __align__(16) u16 Ash[64 * 40];
  __shared__ __align__(16) u16 Asl[64 * 40];
  __shared__ __align__(16) u16 Bsh[64 * 40];
  __shared__ __align__(16) u16 Bsl[64 * 40];
  const int tid  = threadIdx.x;
  const int m0   = blockIdx.x * 64;
  const int y    = blockIdx.y;
  const bool isHm = (y < 4);
  const int n0   = (isHm ? y : (y - 4)) * 64;
  const u16* Bh  = isHm ? Wmh_h : Whh_h;
  const u16* Bl  = isHm ? Wmh_l : Whh_l;
  const float* bias = isHm ? nullptr : b_hh;
  float* C       = isHm ? Hm : gh;
  const int ldc  = isHm ? 256 : 768;

  const int lane = tid & 63;
  const int wv   = tid >> 6;
  const int wm   = wv & 1;          // 32-row half
  const int wn   = wv >> 1;         // 32-col half
  const int q    = lane >> 4;
  const int cl   = lane & 15;

  floatx4 acc[2][2];
#pragma unroll
  for (int i = 0; i < 2; ++i)
#pragma unroll
    for (int j = 0; j < 2; ++j)
      acc[i][j] = (floatx4){0.f, 0.f, 0.f, 0.f};

  const int srow = tid >> 2;          // 0..63
  const int scol = (tid & 3) * 8;     // 0,8,16,24

  for (int kb = 0; kb < 256; kb += 32) {
    {
      const long ar = (long)(m0 + srow) * 256 + kb + scol;
      *(short8*)&Ash[srow * 40 + scol] = *(const short8*)(h_h + ar);
      *(short8*)&Asl[srow * 40 + scol] = *(const short8*)(h_l + ar);
      const long br = (long)(n0 + srow) * 256 + kb + scol;
      *(short8*)&Bsh[srow * 40 + scol] = *(const short8*)(Bh + br);
      *(short8*)&Bsl[srow * 40 + scol] = *(const short8*)(Bl + br);
    }
    __syncthreads();

    short8 ah[2], al[2], bh[2], bl[2];
#pragma unroll
    for (int mi = 0; mi < 2; ++mi) {
      ah[mi] = *(const short8*)&Ash[(wm * 32 + mi * 16 + cl) * 40 + q * 8];
      al[mi] = *(const short8*)&Asl[(wm * 32 + mi * 16 + cl) * 40 + q * 8];
    }
#pragma unroll
    for (int ni = 0; ni < 2; ++ni) {
      bh[ni] = *(const short8*)&Bsh[(wn * 32 + ni * 16 + cl) * 40 + q * 8];
      bl[ni] = *(const short8*)&Bsl[(wn * 32 + ni * 16 + cl) * 40 + q * 8];
    }
#pragma unroll
    for (int mi = 0; mi < 2; ++mi)
#pragma unroll
      for (int ni = 0; ni < 2; ++ni) {
        acc[mi][ni] = __builtin_amdgcn_mfma_f32_16x16x32_bf16(ah[mi], bh[ni], acc[mi][ni], 0, 0, 0);
        acc[mi][ni] = __builtin_amdgcn_mfma_f32_16x16x32_bf16(al[mi], bh[ni], acc[mi][ni], 0, 0, 0);
        acc[mi][ni] = __builtin_amdgcn_mfma_f32_16x16x32_bf16(ah[mi], bl[ni], acc[mi][ni], 0, 0, 0);
      }
    __syncthreads();
  }

#pragma unroll
  for (int mi = 0; mi < 2; ++mi) {
    const int row = m0 + wm * 32 + mi * 16 + q * 4;
#pragma unroll
    for (int ni = 0; ni < 2; ++ni) {
      const int col = n0 + wn * 32 + ni * 16 + cl;
      const float b = bias ? bias[col] : 0.f;
#pragma unroll
      for (int r = 0; r < 4; ++r)
        C[(long)(row + r) * ldc + col] = acc[mi][ni][r] + b;
    }
  }
}

// ---------------------------------------------------------------------------
// One-shot weight prep: casts/splits + (W_me @ W_er) + node split + W_ihT.
// ---------------------------------------------------------------------------
__device__ __forceinline__
void cast_pad_dev(u16* __restrict__ dst, const float* __restrict__ src,
                  int rows, int sc, int dc, int stride, int idx)
{
  if (idx >= rows * dc) return;
  int r = idx / dc, c = idx - r * dc;
  float v = (c < sc) ? src[r * stride + c] : 0.f;
  dst[idx] = f2bf(v);
}

__device__ __forceinline__
void cast_split_dev(u16* __restrict__ dh, u16* __restrict__ dl,
                    const float* __restrict__ src,
                    int rows, int sc, int dc, int stride, int idx)
{
  if (idx >= rows * dc) return;
  int r = idx / dc, c = idx - r * dc;
  float v = (c < sc) ? src[r * stride + c] : 0.f;
  u16 hi = f2bf(v);
  dh[idx] = hi;
  dl[idx] = f2bf(v - bf2f(hi));
}

__global__ __launch_bounds__(256)
void prep_all_k(const float* __restrict__ W_er, const float* __restrict__ Wl1,
                const float* __restrict__ Wl2, const float* __restrict__ W_nr,
                const float* __restrict__ W_m, const float* __restrict__ W_ih,
                const float* __restrict__ W_hh, const float* __restrict__ W_r,
                const float* __restrict__ b_er, const float* __restrict__ b_m,
                const float* __restrict__ node,
                u16* __restrict__ Wcomb, u16* __restrict__ Wl1b,
                u16* __restrict__ Wl2b,
                u16* __restrict__ Wnr_h, u16* __restrict__ Wnr_l,
                u16* __restrict__ Wmh_h, u16* __restrict__ Wmh_l,
                float* __restrict__ WihT,
                u16* __restrict__ Whh_h, u16* __restrict__ Whh_l,
                u16* __restrict__ Wr_h, u16* __restrict__ Wr_l,
                u16* __restrict__ node_h, u16* __restrict__ node_l,
                float* __restrict__ cmb)
{
  const int j = blockIdx.y;
  if (j == 8) {
    if (blockIdx.x >= 256) return;
    const int o = blockIdx.x;
    const int t = threadIdx.x;
    __shared__ float wme[256];
    wme[t] = W_m[o * 512 + 256 + t];
    __syncthreads();
    if (t < 224) {
      float s = 0.f;
      if (t < 200) {
        for (int c = 0; c < 256; ++c) s += wme[c] * W_er[c * 200 + t];
      }
      Wcomb[(256 + o) * 224 + t] = f2bf(s);
    }
    if (t == 0) {
      float s = 0.f;
      for (int c = 0; c < 256; ++c) s += wme[c] * b_er[c];
      cmb[o] = s + b_m[o];
    }
    return;
  }
  const int idx = blockIdx.x * 256 + threadIdx.x;
  switch (j) {
    case 0: cast_pad_dev(Wcomb, W_er, 256, 200, 224, 200, idx); break;
    case 1: cast_pad_dev(Wl1b, Wl1, 512, 256, 256, 256, idx); break;
    case 2: cast_pad_dev(Wl2b, Wl2, 512, 512, 512, 512, idx); break;
    case 3: cast_split_dev(Wnr_h, Wnr_l, W_nr, 256, 100, 128, 100, idx); break;
    case 4: cast_split_dev(Wmh_h, Wmh_l, W_m, 256, 256, 256, 512, idx); break;
    case 5: {  // W_ihT fp32 transpose: WihT[k*768+o] = W_ih[o*256+k]
      if (idx < 196608) {
        const int k = idx / 768;
        const int o = idx - k * 768;
        WihT[idx] = W_ih[o * 256 + k];
      }
    } break;
    case 6: cast_split_dev(Whh_h, Whh_l, W_hh, 768, 256, 256, 256, idx); break;
    case 7: cast_split_dev(Wr_h, Wr_l, W_r, 117, 256, 256, 256, idx); break;
    case 9: cast_split_dev(node_h, node_l, node, 1024, 100, 128, 100, idx); break;
  }
}

extern "C" void kernel_launch(void* const* d_in, const int* in_sizes, int n_in,
                              void* d_out, int out_size, void* d_ws, size_t ws_size,
                              hipStream_t stream)
{
  const float* edge = (const float*)d_in[0];
  const float* node = (const float*)d_in[1];
  const float* W_er = (const float*)d_in[2];
  const float* b_er = (const float*)d_in[3];
  const float* W_nr = (const float*)d_in[4];
  const float* b_nr = (const float*)d_in[5];
  const float* Wl1  = (const float*)d_in[6];
  const float* bl1  = (const float*)d_in[7];
  const float* Wl2  = (const float*)d_in[8];
  const float* bl2  = (const float*)d_in[9];
  const float* Wl3  = (const float*)d_in[10];
  const float* bl3  = (const float*)d_in[11];
  const float* W_m  = (const float*)d_in[12];
  const float* b_m  = (const float*)d_in[13];
  const float* W_ih = (const float*)d_in[14];
  const float* b_ih = (const float*)d_in[15];
  const float* W_hh = (const float*)d_in[16];
  const float* b_hh = (const float*)d_in[17];
  const float* W_r  = (const float*)d_in[18];
  const float* b_r  = (const float*)d_in[19];
  (void)in_sizes; (void)n_in; (void)out_size; (void)ws_size;

  float* out_adj = (float*)d_out;            // [8,128,128]
  float* out_lab = (float*)d_out + 131072;   // [8,128,117]

  char* ws = (char*)d_ws;
  size_t off = 0;
  auto alloc = [&](size_t bytes) -> void* {
    void* p = ws + off; off += (bytes + 255) & ~(size_t)255; return p;
  };
  const long E = 131072;
  u16*   es0  = (u16*)  alloc(E * 256 * 2);
  u16*   es1  = (u16*)  alloc(E * 256 * 2);   // ping-pong partner
  u16*   Em   = (u16*)  alloc(E * 256 * 2);
  float* Hm   = (float*)alloc(1024 * 256 * 4);
  float* hbuf = (float*)alloc(1024 * 256 * 4);
  float* gh   = (float*)alloc(1024 * 768 * 4);
  u16*   h_h  = (u16*)  alloc(1024 * 256 * 2);
  u16*   h_l  = (u16*)  alloc(1024 * 256 * 2);
  u16*   node_h = (u16*)alloc(1024 * 128 * 2);
  u16*   node_l = (u16*)alloc(1024 * 128 * 2);
  u16*   Wcomb = (u16*) alloc(512 * 224 * 2); // [W_er ; W_me@W_er] bf16
  u16*   Wl1b = (u16*)  alloc(512 * 256 * 2);
  u16*   Wl2b = (u16*)  alloc(512 * 512 * 2);
  float* WihT = (float*)alloc(256 * 768 * 4); // W_ih^T fp32 for tail matvec
  float* cmb  = (float*)alloc(256 * 4);
  u16* Wnr_h = (u16*)alloc(256 * 128 * 2); u16* Wnr_l = (u16*)alloc(256 * 128 * 2);
  u16* Wmh_h = (u16*)alloc(256 * 256 * 2); u16* Wmh_l = (u16*)alloc(256 * 256 * 2);
  u16* Whh_h = (u16*)alloc(768 * 256 * 2); u16* Whh_l = (u16*)alloc(768 * 256 * 2);
  u16* Wr_h  = (u16*)alloc(117 * 256 * 2); u16* Wr_l  = (u16*)alloc(117 * 256 * 2);

  // single fused prep dispatch (10 jobs via blockIdx.y)
  prep_all_k<<<dim3(1024, 10), 256, 0, stream>>>(
      W_er, Wl1, Wl2, W_nr, W_m, W_ih, W_hh, W_r, b_er, b_m, node,
      Wcomb, Wl1b, Wl2b, Wnr_h, Wnr_l, Wmh_h, Wmh_l,
      WihT, Whh_h, Whh_l, Wr_h, Wr_l, node_h, node_l, cmb);

  // es0 (layer-0 e_state) + Em in one pass, edge read once
  fused_front_k<<<2048, dim3(256), 0, stream>>>(edge, Wcomb, b_er, cmb, es0, Em);
  // h0 = node @ W_nr^T + b_nr  (pre-split A; writes fp32 h + split h)
  gemm_ps_k<<<dim3(8, 2), dim3(256), 0, stream>>>(
      node_h, node_l, Wnr_h, Wnr_l, b_nr, hbuf, h_h, h_l, 256, 128, 128, 256);

  u16* esbuf[2] = { es0, es1 };
  for (int p = 0; p < 3; ++p) {
    // Hm = h @ W_mh^T and gh = h @ W_hh^T + b_hh — 64x64 tiles, 256 blocks
    gemm_hm_gh_k<<<dim3(16, 16), dim3(256), 0, stream>>>(
        h_h, h_l, Wmh_h, Wmh_l, Whh_h, Whh_l, b_hh, Hm, gh);
    // fused link MLP + message + aggregation + gi matvec + GRU
    linkmsg_k<<<1024, dim3(512), 0, stream>>>(
        esbuf[p & 1], Wl1b, bl1, Wl2b, bl2, Wl3, bl3,
        Em, Hm, out_adj, esbuf[(p + 1) & 1],
        WihT, b_ih, gh, hbuf, h_h, h_l,
        (p == 2) ? 1 : 0, (p < 2) ? 1 : 0);
  }
  // labels = h @ W_r^T + b_r  (pre-split h)
  gemm_ps_k<<<dim3(8, 1), dim3(256), 0, stream>>>(
      h_h, h_l, Wr_h, Wr_l, b_r, out_lab, nullptr, nullptr, 117, 256, 256, 117);
}

// Round 14
// 765.708 us; speedup vs baseline: 1.2533x; 1.2533x over previous
//
#include <hip/hip_runtime.h>
#include <math.h>

typedef unsigned short u16;
typedef __attribute__((ext_vector_type(8))) short short8;
typedef __attribute__((ext_vector_type(4))) short short4v;
typedef __attribute__((ext_vector_type(4))) float floatx4;

__device__ __forceinline__ float bf2f(u16 u) {
  union { unsigned int i; float f; } v; v.i = ((unsigned int)u) << 16; return v.f;
}
__device__ __forceinline__ u16 f2bf(float f) {
  union { unsigned int i; float f; } v; v.f = f;
  unsigned int i = v.i;
  unsigned int lsb = (i >> 16) & 1u;
  i += 0x7fffu + lsb;          // round-to-nearest-even
  return (u16)(i >> 16);
}

// ---------------------------------------------------------------------------
// Fused front GEMM (R12 swapped-operand form + setprio).
// ---------------------------------------------------------------------------
__global__ __launch_bounds__(256, 2)
void fused_front_k(const float* __restrict__ edge, const u16* __restrict__ Wcomb,
                   const float* __restrict__ b_er, const float* __restrict__ cmb,
                   u16* __restrict__ es, u16* __restrict__ Em)
{
  __shared__ __align__(16) u16 As[64 * 232];
  const int tid  = threadIdx.x;
  const int lane = tid & 63;
  const int wv   = tid >> 6;
  const int q    = lane >> 4;
  const int cl   = lane & 15;
  const long r0  = (long)blockIdx.x * 64;

  for (int z = tid; z < 64 * 24; z += 256) {
    const int zr = z / 24;
    As[zr * 232 + 200 + (z - zr * 24)] = 0;
  }
  const float4* src = (const float4*)(edge + r0 * 200);
  for (int it = tid; it < 3200; it += 256) {
    const float4 v = src[it];
    const int row = it / 50;
    const int c4  = it - row * 50;
    u16 t[4] = { f2bf(v.x), f2bf(v.y), f2bf(v.z), f2bf(v.w) };
    *(short4v*)&As[row * 232 + c4 * 4] = *(short4v*)t;
  }
  __syncthreads();

  floatx4 acc[8][4];   // [wtile over 128 out-cols][rtile over 64 rows]
#pragma unroll
  for (int wi = 0; wi < 8; ++wi)
#pragma unroll
    for (int ri = 0; ri < 4; ++ri)
      acc[wi][ri] = (floatx4){0.f, 0.f, 0.f, 0.f};

  short8 b0[8], b1[8];
#pragma unroll
  for (int wi = 0; wi < 8; ++wi)
    b0[wi] = *(const short8*)(Wcomb + (long)(wv * 128 + wi * 16 + cl) * 224 + q * 8);
#pragma unroll
  for (int ks = 0; ks < 7; ++ks) {
    short8* bc = (ks & 1) ? b1 : b0;
    short8* bn = (ks & 1) ? b0 : b1;
    if (ks < 6) {
      const int kb = (ks + 1) * 32;
#pragma unroll
      for (int wi = 0; wi < 8; ++wi)
        bn[wi] = *(const short8*)(Wcomb + (long)(wv * 128 + wi * 16 + cl) * 224 + kb + q * 8);
    }
    short8 a[4];
#pragma unroll
    for (int ri = 0; ri < 4; ++ri)
      a[ri] = *(const short8*)&As[(ri * 16 + cl) * 232 + ks * 32 + q * 8];
    __builtin_amdgcn_s_setprio(1);
#pragma unroll
    for (int wi = 0; wi < 8; ++wi)
#pragma unroll
      for (int ri = 0; ri < 4; ++ri)
        acc[wi][ri] = __builtin_amdgcn_mfma_f32_16x16x32_bf16(bc[wi], a[ri], acc[wi][ri], 0, 0, 0);
    __builtin_amdgcn_s_setprio(0);
  }

  const bool is_ef   = (wv < 2);
  const float* bias  = is_ef ? b_er : cmb;
  u16* dst           = is_ef ? es : Em;
  const int colbase  = (wv & 1) * 128;
#pragma unroll
  for (int wi = 0; wi < 8; ++wi) {
    const int c0i = colbase + wi * 16 + q * 4;    // 4 consecutive out-cols
    const float4 bv = *(const float4*)&bias[c0i];
    const float bb[4] = {bv.x, bv.y, bv.z, bv.w};
#pragma unroll
    for (int ri = 0; ri < 4; ++ri) {
      const int row = ri * 16 + cl;
      u16 p[4];
#pragma unroll
      for (int r = 0; r < 4; ++r)
        p[r] = f2bf(acc[wi][ri][r] + bb[r]);
      *(short4v*)&dst[(r0 + row) * 256 + c0i] = *(short4v*)p;
    }
  }
}

// ---------------------------------------------------------------------------
// linkmsg: link MLP + message + aggregation fused (R15/R16 form, reverted
// from R17 — the in-kernel gi matvec was a serial L2-latency loop, +82 us).
// ---------------------------------------------------------------------------
__global__ __launch_bounds__(512, 2)
void linkmsg_k(const u16* __restrict__ es, const u16* __restrict__ Wl1b,
               const float* __restrict__ bl1, const u16* __restrict__ Wl2b,
               const float* __restrict__ bl2, const float* __restrict__ wl3,
               const float* __restrict__ bl3, const u16* __restrict__ Em,
               const float* __restrict__ Hm, float* __restrict__ adj,
               u16* __restrict__ esn,
               u16* __restrict__ msum_h, u16* __restrict__ msum_l,
               const int write_adj, const int write_es)
{
  __shared__ __align__(16) u16 x1b[128 * 512];   // 128 KB; [0,64K) doubles as es tile
  const int tid  = threadIdx.x;
  const int lane = tid & 63;
  const int wv   = tid >> 6;        // wave 0..7 -> 64-out-col slice
  const int q    = lane >> 4;
  const int cl   = lane & 15;
  const int nw0  = wv * 64;
  const long r0  = (long)blockIdx.x * 128;

  // ---- stage es tile [128 x 256 bf16] = 64 KB into LDS, swizzled ----
  {
    const short8* gsrc = (const short8*)(es + r0 * 256);   // 4096 16B-chunks
#pragma unroll
    for (int i = 0; i < 8; ++i) {
      const int g   = tid + i * 512;
      const int row = g >> 5;          // 32 chunks per row
      const int c   = g & 31;
      const short8 v = gsrc[g];
      *(short8*)&x1b[row * 256 + ((c ^ (row & 15)) << 3)] = v;
    }
  }

  floatx4 acc[4][8];   // [wtile over 64 out-cols][rtile over 128 rows]
#pragma unroll
  for (int ni = 0; ni < 4; ++ni)
#pragma unroll
    for (int mi = 0; mi < 8; ++mi)
      acc[ni][mi] = (floatx4){0.f, 0.f, 0.f, 0.f};

  // first weight fragments can load while staging completes
  short8 b0[4], b1[4];
#pragma unroll
  for (int ni = 0; ni < 4; ++ni)
    b0[ni] = *(const short8*)(Wl1b + (nw0 + ni * 16 + cl) * 256 + q * 8);
  __syncthreads();

  // ---------------- phase 1: x1^T = Wl1 @ es^T (swapped operands) --------
  {
#pragma unroll
    for (int ks = 0; ks < 8; ++ks) {
      short8* bc = (ks & 1) ? b1 : b0;
      short8* bn = (ks & 1) ? b0 : b1;
      if (ks < 7) {
        const int kb = (ks + 1) * 32;
#pragma unroll
        for (int ni = 0; ni < 4; ++ni)
          bn[ni] = *(const short8*)(Wl1b + (nw0 + ni * 16 + cl) * 256 + kb + q * 8);
      }
      short8 a[8];
#pragma unroll
      for (int mi = 0; mi < 8; ++mi) {
        const int row = mi * 16 + cl;
        a[mi] = *(const short8*)&x1b[row * 256 + (((ks * 4 + q) ^ cl) << 3)];
      }
      __builtin_amdgcn_s_setprio(1);
#pragma unroll
      for (int ni = 0; ni < 4; ++ni)
#pragma unroll
        for (int mi = 0; mi < 8; ++mi)
          acc[ni][mi] = __builtin_amdgcn_mfma_f32_16x16x32_bf16(bc[ni], a[mi], acc[ni][mi], 0, 0, 0);
      __builtin_amdgcn_s_setprio(0);
    }
  }
  __syncthreads();   // all waves done READING the es tile before x1 overwrites it

  // epilogue 1: packed b64 x1 writes. Lane's 4 acc values = out-cols
  // ocb..ocb+3 of row (mi*16+cl); all 4 stay in one swizzle chunk.
  {
#pragma unroll
    for (int ni = 0; ni < 4; ++ni) {
      const int ocb   = nw0 + ni * 16 + q * 4;
      const float4 bv = *(const float4*)&bl1[ocb];
      const float bb[4] = {bv.x, bv.y, bv.z, bv.w};
      const int chunk = ocb >> 3;
      const int off   = ocb & 7;
#pragma unroll
      for (int mi = 0; mi < 8; ++mi) {
        const int row = mi * 16 + cl;          // row&15 == cl
        u16 p[4];
#pragma unroll
        for (int r = 0; r < 4; ++r)
          p[r] = f2bf(fmaxf(acc[ni][mi][r] + bb[r], 0.f));
        *(short4v*)&x1b[row * 512 + ((chunk ^ cl) << 3) + off] = *(short4v*)p;
      }
    }
  }
#pragma unroll
  for (int ni = 0; ni < 4; ++ni)
#pragma unroll
    for (int mi = 0; mi < 8; ++mi)
      acc[ni][mi] = (floatx4){0.f, 0.f, 0.f, 0.f};
  __syncthreads();

  // ---------------- phase 2: D^T = Wl2 @ x1^T (swapped operands) ---------
  {
    short8 c0[4], c1[4];
#pragma unroll
    for (int ni = 0; ni < 4; ++ni)
      c0[ni] = *(const short8*)(Wl2b + (nw0 + ni * 16 + cl) * 512 + q * 8);
#pragma unroll
    for (int ks = 0; ks < 16; ++ks) {
      short8* cc = (ks & 1) ? c1 : c0;
      short8* cn = (ks & 1) ? c0 : c1;
      if (ks < 15) {
        const int kb = (ks + 1) * 32;
#pragma unroll
        for (int ni = 0; ni < 4; ++ni)
          cn[ni] = *(const short8*)(Wl2b + (nw0 + ni * 16 + cl) * 512 + kb + q * 8);
      }
      short8 a[8];
#pragma unroll
      for (int mi = 0; mi < 8; ++mi) {
        const int row = mi * 16 + cl;
        a[mi] = *(const short8*)&x1b[row * 512 + (((ks * 4 + q) ^ cl) << 3)];
      }
      __builtin_amdgcn_s_setprio(1);
#pragma unroll
      for (int ni = 0; ni < 4; ++ni)
#pragma unroll
        for (int mi = 0; mi < 8; ++mi)
          acc[ni][mi] = __builtin_amdgcn_mfma_f32_16x16x32_bf16(cc[ni], a[mi], acc[ni][mi], 0, 0, 0);
      __builtin_amdgcn_s_setprio(0);
    }
  }

  // epilogue 2: relu(+bl2), dot wl3. Lane holds 16 out-cols of row
  // (mi*16+cl) -> serial 16-term sums, then 2-level shuffle over q only.
  float pv[8];
#pragma unroll
  for (int mi = 0; mi < 8; ++mi) pv[mi] = 0.f;
#pragma unroll
  for (int ni = 0; ni < 4; ++ni) {
    const int ocb   = nw0 + ni * 16 + q * 4;
    const float4 b2 = *(const float4*)&bl2[ocb];
    const float4 w3 = *(const float4*)&wl3[ocb];
    const float bb[4] = {b2.x, b2.y, b2.z, b2.w};
    const float ww[4] = {w3.x, w3.y, w3.z, w3.w};
#pragma unroll
    for (int mi = 0; mi < 8; ++mi) {
#pragma unroll
      for (int r = 0; r < 4; ++r)
        pv[mi] += fmaxf(acc[ni][mi][r] + bb[r], 0.f) * ww[r];
    }
  }
  __syncthreads();                    // all x1b reads done; reuse as scratch
  float* pf   = (float*)x1b;          // [8 waves][128 rows]  (4 KB)
  float* sigv = pf + 1024;            // 128 floats           (at 4 KB)
  float* red  = pf + 2048;            // 4096 floats          (at 8 KB)
#pragma unroll
  for (int mi = 0; mi < 8; ++mi) {
    float p = pv[mi];
    p += __shfl_xor(p, 16, 64);
    p += __shfl_xor(p, 32, 64);
    if (q == 0) pf[wv * 128 + mi * 16 + cl] = p;
  }
  __syncthreads();
  if (tid < 128) {
    float s = bl3[0];
#pragma unroll
    for (int w = 0; w < 8; ++w) s += pf[w * 128 + tid];
    if (write_adj) adj[r0 + tid] = s;
    sigv[tid] = 1.f / (1.f + __expf(-s));
  }
  __syncthreads();

  // ---------------- message tail: M = relu(Em + Hm)*sig; scatter + sum ----
  const int b  = (int)(blockIdx.x >> 7);
  const int i  = (int)(blockIdx.x & 127);
  const int g  = tid >> 5;          // stripe 0..15
  const int c8 = (tid & 31) * 8;    // col block
  float msacc[8] = {0.f, 0.f, 0.f, 0.f, 0.f, 0.f, 0.f, 0.f};
  for (int w0 = 0; w0 < 128; w0 += 16) {
    const int w = w0 + g;
    const float s = sigv[w];
    const short8 ev = *(const short8*)(Em + (r0 + w) * 256 + c8);
    const float4 h0 = *(const float4*)(Hm + ((long)(b * 128 + w)) * 256 + c8);
    const float4 h1 = *(const float4*)(Hm + ((long)(b * 128 + w)) * 256 + c8 + 4);
    const float hv[8] = {h0.x, h0.y, h0.z, h0.w, h1.x, h1.y, h1.z, h1.w};
    u16 mb[8];
#pragma unroll
    for (int j = 0; j < 8; ++j) {
      float x = fmaxf(bf2f(((const u16*)&ev)[j]) + hv[j], 0.f) * s;
      msacc[j] += x;
      mb[j] = f2bf(x);
    }
    if (write_es)
      *(short8*)(esn + (((long)(b * 128 + w)) * 128 + i) * 256 + c8) = *(short8*)mb;
  }
  // red[tid*8 + j] holds col ((tid&31)*8+j) of stripe (tid>>5);
  // reader index for col t, stripe g is red[g*256 + t] (stride-1 reads).
  {
    float4 m0 = {msacc[0], msacc[1], msacc[2], msacc[3]};
    float4 m1 = {msacc[4], msacc[5], msacc[6], msacc[7]};
    *(float4*)&red[tid * 8]     = m0;
    *(float4*)&red[tid * 8 + 4] = m1;
  }
  __syncthreads();
  if (tid < 256) {
    float s = 0.f;
#pragma unroll
    for (int gg = 0; gg < 16; ++gg) s += red[gg * 256 + tid];
    const long o = ((long)(b * 128 + i)) * 256 + tid;
    const u16 hi = f2bf(s);
    msum_h[o] = hi;
    msum_l[o] = f2bf(s - bf2f(hi));
  }
}

// ---------------------------------------------------------------------------
// R18: generic 64x64-tile pre-split GEMM (hm_gh's proven body, parameterized)
// — used for h0 (grid 16x4) and labels (grid 16x2). Replaces the 128-tile
// gemm_ps_k whose 16/8-block grids idled >=94% of CUs. Same 3-MFMA split and
// kb order -> bit-identical per-element results.
// ---------------------------------------------------------------------------
__global__ __launch_bounds__(256, 2)
void gemm_ps64_k(const u16* __restrict__ Ah, const u16* __restrict__ Al,
                 const u16* __restrict__ Bh, const u16* __restrict__ Bl,
                 const float* __restrict__ bias,
                 float* __restrict__ C, u16* __restrict__ Ch, u16* __restrict__ Cl,
                 int N, int K, int lda, int ldc)
{
  __shared__ __align__(16) u16 Ash[64 * 40];
  __shared__ __align__(16) u16 Asl[64 * 40];
  __shared__ __align__(16) u16 Bsh[64 * 40];
  __shared__ __align__(16) u16 Bsl[64 * 40];
  const int tid  = threadIdx.x;
  const int m0   = blockIdx.x * 64;
  const int n0   = blockIdx.y * 64;
  const int lane = tid & 63;
  const int wv   = tid >> 6;
  const int wm   = wv & 1;          // 32-row half
  const int wn   = wv >> 1;         // 32-col half
  const int q    = lane >> 4;
  const int cl   = lane & 15;

  floatx4 acc[2][2];
#pragma unroll
  for (int i = 0; i < 2; ++i)
#pragma unroll
    for (int j = 0; j < 2; ++j)
      acc[i][j] = (floatx4){0.f, 0.f, 0.f, 0.f};

  const int srow = tid >> 2;          // 0..63
  const int scol = (tid & 3) * 8;     // 0,8,16,24

  for (int kb = 0; kb < K; kb += 32) {
    {
      const long ar = (long)(m0 + srow) * lda + kb + scol;
      *(short8*)&Ash[srow * 40 + scol] = *(const short8*)(Ah + ar);
      *(short8*)&Asl[srow * 40 + scol] = *(const short8*)(Al + ar);
      const int n = n0 + srow;
      u16* dh = &Bsh[srow * 40 + scol];
      u16* dl = &Bsl[srow * 40 + scol];
      if (n < N) {
        const long br = (long)n * K + kb + scol;
        *(short8*)dh = *(const short8*)(Bh + br);
        *(short8*)dl = *(const short8*)(Bl + br);
      } else {
#pragma unroll
        for (int j = 0; j < 8; ++j) { dh[j] = 0; dl[j] = 0; }
      }
    }
    __syncthreads();

    short8 ah[2], al[2], bh[2], bl[2];
#pragma unroll
    for (int mi = 0; mi < 2; ++mi) {
      ah[mi] = *(const short8*)&Ash[(wm * 32 + mi * 16 + cl) * 40 + q * 8];
      al[mi] = *(const short8*)&Asl[(wm * 32 + mi * 16 + cl) * 40 + q * 8];
    }
#pragma unroll
    for (int ni = 0; ni < 2; ++ni) {
      bh[ni] = *(const short8*)&Bsh[(wn * 32 + ni * 16 + cl) * 40 + q * 8];
      bl[ni] = *(const short8*)&Bsl[(wn * 32 + ni * 16 + cl) * 40 + q * 8];
    }
#pragma unroll
    for (int mi = 0; mi < 2; ++mi)
#pragma unroll
      for (int ni = 0; ni < 2; ++ni) {
        acc[mi][ni] = __builtin_amdgcn_mfma_f32_16x16x32_bf16(ah[mi], bh[ni], acc[mi][ni], 0, 0, 0);
        acc[mi][ni] = __builtin_amdgcn_mfma_f32_16x16x32_bf16(al[mi], bh[ni], acc[mi][ni], 0, 0, 0);
        acc[mi][ni] = __builtin_amdgcn_mfma_f32_16x16x32_bf16(ah[mi], bl[ni], acc[mi][ni], 0, 0, 0);
      }
    __syncthreads();
  }

#pragma unroll
  for (int mi = 0; mi < 2; ++mi) {
    const int row = m0 + wm * 32 + mi * 16 + q * 4;
#pragma unroll
    for (int ni = 0; ni < 2; ++ni) {
      const int col = n0 + wn * 32 + ni * 16 + cl;
      if (col < N) {
        const float b = bias ? bias[col] : 0.f;
#pragma unroll
        for (int r = 0; r < 4; ++r) {
          float v = acc[mi][ni][r] + b;
          const long o = (long)(row + r) * ldc + col;
          C[o] = v;
          if (Ch) {
            const u16 hi = f2bf(v);
            Ch[o] = hi;
            Cl[o] = f2bf(v - bf2f(hi));
          }
        }
      }
    }
  }
}

// Hm/gh GEMM, 64x64 tiles, grid (16,16) = 256 blocks (R16 form).
__global__ __launch_bounds__(256, 2)
void gemm_hm_gh_k(const u16* __restrict__ h_h, const u16* __restrict__ h_l,
                  const u16* __restrict__ Wmh_h, const u16* __restrict__ Wmh_l,
                  const u16* __restrict__ Whh_h, const u16* __restrict__ Whh_l,
                  const float* __restrict__ b_hh,
                  float* __restrict__ Hm, float* __restrict__ gh)
{
  __shared__ __align__(16) u16 Ash[64 * 40];
  __shared__ __align__(16) u16 Asl[64 * 40];
  __shared__ __align__(16) u16 Bsh[64 * 40];
  __shared__ __align__(16) u16 Bsl[64 * 40];
  const int tid  = threadIdx.x;
  const int m0   = blockIdx.x * 64;
  const int y    = blockIdx.y;
  const bool isHm = (y < 4);
  const int n0   = (isHm ? y : (y - 4)) * 64;
  const u16* Bh  = isHm ? Wmh_h : Whh_h;
  const u16* Bl  = isHm ? Wmh_l : Whh_l;
  const float* bias = isHm ? nullptr : b_hh;
  float* C       = isHm ? Hm : gh;
  const int ldc  = isHm ? 256 : 768;

  const int lane = tid & 63;
  const int wv   = tid >> 6;
  const int wm   = wv & 1;          // 32-row half
  const int wn   = wv >> 1;         // 32-col half
  const int q    = lane >> 4;
  const int cl   = lane & 15;

  floatx4 acc[2][2];
#pragma unroll
  for (int i = 0; i < 2; ++i)
#pragma unroll
    for (int j = 0; j < 2; ++j)
      acc[i][j] = (floatx4){0.f, 0.f, 0.f, 0.f};

  const int srow = tid >> 2;          // 0..63
  const int scol = (tid & 3) * 8;     // 0,8,16,24

  for (int kb = 0; kb < 256; kb += 32) {
    {
      const long ar = (long)(m0 + srow) * 256 + kb + scol;
      *(short8*)&Ash[srow * 40 + scol] = *(const short8*)(h_h + ar);
      *(short8*)&Asl[srow * 40 + scol] = *(const short8*)(h_l + ar);
      const long br = (long)(n0 + srow) * 256 + kb + scol;
      *(short8*)&Bsh[srow * 40 + scol] = *(const short8*)(Bh + br);
      *(short8*)&Bsl[srow * 40 + scol] = *(const short8*)(Bl + br);
    }
    __syncthreads();

    short8 ah[2], al[2], bh[2], bl[2];
#pragma unroll
    for (int mi = 0; mi < 2; ++mi) {
      ah[mi] = *(const short8*)&Ash[(wm * 32 + mi * 16 + cl) * 40 + q * 8];
      al[mi] = *(const short8*)&Asl[(wm * 32 + mi * 16 + cl) * 40 + q * 8];
    }
#pragma unroll
    for (int ni = 0; ni < 2; ++ni) {
      bh[ni] = *(const short8*)&Bsh[(wn * 32 + ni * 16 + cl) * 40 + q * 8];
      bl[ni] = *(const short8*)&Bsl[(wn * 32 + ni * 16 + cl) * 40 + q * 8];
    }
#pragma unroll
    for (int mi = 0; mi < 2; ++mi)
#pragma unroll
      for (int ni = 0; ni < 2; ++ni) {
        acc[mi][ni] = __builtin_amdgcn_mfma_f32_16x16x32_bf16(ah[mi], bh[ni], acc[mi][ni], 0, 0, 0);
        acc[mi][ni] = __builtin_amdgcn_mfma_f32_16x16x32_bf16(al[mi], bh[ni], acc[mi][ni], 0, 0, 0);
        acc[mi][ni] = __builtin_amdgcn_mfma_f32_16x16x32_bf16(ah[mi], bl[ni], acc[mi][ni], 0, 0, 0);
      }
    __syncthreads();
  }

#pragma unroll
  for (int mi = 0; mi < 2; ++mi) {
    const int row = m0 + wm * 32 + mi * 16 + q * 4;
#pragma unroll
    for (int ni = 0; ni < 2; ++ni) {
      const int col = n0 + wn * 32 + ni * 16 + cl;
      const float b = bias ? bias[col] : 0.f;
#pragma unroll
      for (int r = 0; r < 4; ++r)
        C[(long)(row + r) * ldc + col] = acc[mi][ni][r] + b;
    }
  }
}

// ---------------------------------------------------------------------------
// Fused gi-GEMM + GRU, 64x32 col-tiles, grid (16,8) = 128 blocks (R16 form).
// ---------------------------------------------------------------------------
__global__ __launch_bounds__(256, 2)
void gemm_gru_k(const u16* __restrict__ Ah, const u16* __restrict__ Al, // msum split [1024 x 256]
                const u16* __restrict__ Bh, const u16* __restrict__ Bl, // Wih split [768 x 256]
                const float* __restrict__ b_ih,
                const float* __restrict__ gh,     // [1024 x 768] (incl b_hh)
                float* __restrict__ h,            // [1024 x 256] in/out (fp32)
                u16* __restrict__ h_h, u16* __restrict__ h_l)
{
  __shared__ __align__(16) u16 Ash[64 * 40];
  __shared__ __align__(16) u16 Asl[64 * 40];
  __shared__ __align__(16) u16 Bsh[96 * 40];
  __shared__ __align__(16) u16 Bsl[96 * 40];
  const int tid  = threadIdx.x;
  const int m0   = blockIdx.x * 64;
  const int cb   = blockIdx.y * 32;    // col block within D=256
  const int lane = tid & 63;
  const int wv   = tid >> 6;           // 16-row slice
  const int q    = lane >> 4;
  const int cl   = lane & 15;

  floatx4 acc[3][2];
#pragma unroll
  for (int g = 0; g < 3; ++g)
#pragma unroll
    for (int ni = 0; ni < 2; ++ni)
      acc[g][ni] = (floatx4){0.f, 0.f, 0.f, 0.f};

  const int srow = tid >> 2;          // 0..63
  const int scol = (tid & 3) * 8;     // 0,8,16,24

  for (int kb = 0; kb < 256; kb += 32) {
    // A stage: pre-split short8 copies (64 x 32)
    {
      const long ar = (long)(m0 + srow) * 256 + kb + scol;
      *(short8*)&Ash[srow * 40 + scol] = *(const short8*)(Ah + ar);
      *(short8*)&Asl[srow * 40 + scol] = *(const short8*)(Al + ar);
    }
    // B stage: 96 rows (3 gates x 32) x 32 cols = 384 short8 tasks per buffer
    for (int s = tid; s < 384; s += 256) {
      const int br = s >> 2;               // 0..95
      const int bc = (s & 3) * 8;
      const long wrow = (long)((br >> 5) * 256 + cb + (br & 31));
      *(short8*)&Bsh[br * 40 + bc] = *(const short8*)(Bh + wrow * 256 + kb + bc);
      *(short8*)&Bsl[br * 40 + bc] = *(const short8*)(Bl + wrow * 256 + kb + bc);
    }
    __syncthreads();

    const short8 ah = *(const short8*)&Ash[(wv * 16 + cl) * 40 + q * 8];
    const short8 al = *(const short8*)&Asl[(wv * 16 + cl) * 40 + q * 8];
#pragma unroll
    for (int g = 0; g < 3; ++g)
#pragma unroll
      for (int ni = 0; ni < 2; ++ni) {
        const short8 bh = *(const short8*)&Bsh[(g * 32 + ni * 16 + cl) * 40 + q * 8];
        const short8 bl = *(const short8*)&Bsl[(g * 32 + ni * 16 + cl) * 40 + q * 8];
        acc[g][ni] = __builtin_amdgcn_mfma_f32_16x16x32_bf16(ah, bh, acc[g][ni], 0, 0, 0);
        acc[g][ni] = __builtin_amdgcn_mfma_f32_16x16x32_bf16(al, bh, acc[g][ni], 0, 0, 0);
        acc[g][ni] = __builtin_amdgcn_mfma_f32_16x16x32_bf16(ah, bl, acc[g][ni], 0, 0, 0);
      }
    __syncthreads();
  }

  // GRU epilogue, fully in-register per element
#pragma unroll
  for (int ni = 0; ni < 2; ++ni) {
    const int col = cb + ni * 16 + cl;
    const float bi_r = b_ih[col];
    const float bi_z = b_ih[256 + col];
    const float bi_n = b_ih[512 + col];
#pragma unroll
    for (int r = 0; r < 4; ++r) {
      const int row = m0 + wv * 16 + q * 4 + r;
      const long gb = (long)row * 768;
      const float gr = (acc[0][ni][r] + bi_r) + gh[gb + col];
      const float gz = (acc[1][ni][r] + bi_z) + gh[gb + 256 + col];
      const float rv = 1.f / (1.f + __expf(-gr));
      const float zv = 1.f / (1.f + __expf(-gz));
      const float nv = tanhf((acc[2][ni][r] + bi_n) + rv * gh[gb + 512 + col]);
      const int hidx = row * 256 + col;
      const float hv = (1.f - zv) * nv + zv * h[hidx];
      h[hidx] = hv;
      const u16 hh = f2bf(hv);
      h_h[hidx] = hh;
      h_l[hidx] = f2bf(hv - bf2f(hh));
    }
  }
}

// ---------------------------------------------------------------------------
// One-shot weight prep: all casts/splits + (W_me @ W_er) + node split.
// ---------------------------------------------------------------------------
__device__ __forceinline__
void cast_pad_dev(u16* __restrict__ dst, const float* __restrict__ src,
                  int rows, int sc, int dc, int stride, int idx)
{
  if (idx >= rows * dc) return;
  int r = idx / dc, c = idx - r * dc;
  float v = (c < sc) ? src[r * stride + c] : 0.f;
  dst[idx] = f2bf(v);
}

__device__ __forceinline__
void cast_split_dev(u16* __restrict__ dh, u16* __restrict__ dl,
                    const float* __restrict__ src,
                    int rows, int sc, int dc, int stride, int idx)
{
  if (idx >= rows * dc) return;
  int r = idx / dc, c = idx - r * dc;
  float v = (c < sc) ? src[r * stride + c] : 0.f;
  u16 hi = f2bf(v);
  dh[idx] = hi;
  dl[idx] = f2bf(v - bf2f(hi));
}

__global__ __launch_bounds__(256)
void prep_all_k(const float* __restrict__ W_er, const float* __restrict__ Wl1,
                const float* __restrict__ Wl2, const float* __restrict__ W_nr,
                const float* __restrict__ W_m, const float* __restrict__ W_ih,
                const float* __restrict__ W_hh, const float* __restrict__ W_r,
                const float* __restrict__ b_er, const float* __restrict__ b_m,
                const float* __restrict__ node,
                u16* __restrict__ Wcomb, u16* __restrict__ Wl1b,
                u16* __restrict__ Wl2b,
                u16* __restrict__ Wnr_h, u16* __restrict__ Wnr_l,
                u16* __restrict__ Wmh_h, u16* __restrict__ Wmh_l,
                u16* __restrict__ Wih_h, u16* __restrict__ Wih_l,
                u16* __restrict__ Whh_h, u16* __restrict__ Whh_l,
                u16* __restrict__ Wr_h, u16* __restrict__ Wr_l,
                u16* __restrict__ node_h, u16* __restrict__ node_l,
                float* __restrict__ cmb)
{
  const int j = blockIdx.y;
  if (j == 8) {
    if (blockIdx.x >= 256) return;
    const int o = blockIdx.x;
    const int t = threadIdx.x;
    __shared__ float wme[256];
    wme[t] = W_m[o * 512 + 256 + t];
    __syncthreads();
    if (t < 224) {
      float s = 0.f;
      if (t < 200) {
        for (int c = 0; c < 256; ++c) s += wme[c] * W_er[c * 200 + t];
      }
      Wcomb[(256 + o) * 224 + t] = f2bf(s);
    }
    if (t == 0) {
      float s = 0.f;
      for (int c = 0; c < 256; ++c) s += wme[c] * b_er[c];
      cmb[o] = s + b_m[o];
    }
    return;
  }
  const int idx = blockIdx.x * 256 + threadIdx.x;
  switch (j) {
    case 0: cast_pad_dev(Wcomb, W_er, 256, 200, 224, 200, idx); break;
    case 1: cast_pad_dev(Wl1b, Wl1, 512, 256, 256, 256, idx); break;
    case 2: cast_pad_dev(Wl2b, Wl2, 512, 512, 512, 512, idx); break;
    case 3: cast_split_dev(Wnr_h, Wnr_l, W_nr, 256, 100, 128, 100, idx); break;
    case 4: cast_split_dev(Wmh_h, Wmh_l, W_m, 256, 256, 256, 512, idx); break;
    case 5: cast_split_dev(Wih_h, Wih_l, W_ih, 768, 256, 256, 256, idx); break;
    case 6: cast_split_dev(Whh_h, Whh_l, W_hh, 768, 256, 256, 256, idx); break;
    case 7: cast_split_dev(Wr_h, Wr_l, W_r, 117, 256, 256, 256, idx); break;
    case 9: cast_split_dev(node_h, node_l, node, 1024, 100, 128, 100, idx); break;
  }
}

extern "C" void kernel_launch(void* const* d_in, const int* in_sizes, int n_in,
                              void* d_out, int out_size, void* d_ws, size_t ws_size,
                              hipStream_t stream)
{
  const float* edge = (const float*)d_in[0];
  const float* node = (const float*)d_in[1];
  const float* W_er = (const float*)d_in[2];
  const float* b_er = (const float*)d_in[3];
  const float* W_nr = (const float*)d_in[4];
  const float* b_nr = (const float*)d_in[5];
  const float* Wl1  = (const float*)d_in[6];
  const float* bl1  = (const float*)d_in[7];
  const float* Wl2  = (const float*)d_in[8];
  const float* bl2  = (const float*)d_in[9];
  const float* Wl3  = (const float*)d_in[10];
  const float* bl3  = (const float*)d_in[11];
  const float* W_m  = (const float*)d_in[12];
  const float* b_m  = (const float*)d_in[13];
  const float* W_ih = (const float*)d_in[14];
  const float* b_ih = (const float*)d_in[15];
  const float* W_hh = (const float*)d_in[16];
  const float* b_hh = (const float*)d_in[17];
  const float* W_r  = (const float*)d_in[18];
  const float* b_r  = (const float*)d_in[19];
  (void)in_sizes; (void)n_in; (void)out_size; (void)ws_size;

  float* out_adj = (float*)d_out;            // [8,128,128]
  float* out_lab = (float*)d_out + 131072;   // [8,128,117]

  char* ws = (char*)d_ws;
  size_t off = 0;
  auto alloc = [&](size_t bytes) -> void* {
    void* p = ws + off; off += (bytes + 255) & ~(size_t)255; return p;
  };
  const long E = 131072;
  u16*   es0  = (u16*)  alloc(E * 256 * 2);
  u16*   es1  = (u16*)  alloc(E * 256 * 2);   // ping-pong partner
  u16*   Em   = (u16*)  alloc(E * 256 * 2);
  float* Hm   = (float*)alloc(1024 * 256 * 4);
  float* hbuf = (float*)alloc(1024 * 256 * 4);
  float* gh   = (float*)alloc(1024 * 768 * 4);
  u16*   h_h  = (u16*)  alloc(1024 * 256 * 2);
  u16*   h_l  = (u16*)  alloc(1024 * 256 * 2);
  u16*   ms_h = (u16*)  alloc(1024 * 256 * 2);
  u16*   ms_l = (u16*)  alloc(1024 * 256 * 2);
  u16*   node_h = (u16*)alloc(1024 * 128 * 2);
  u16*   node_l = (u16*)alloc(1024 * 128 * 2);
  u16*   Wcomb = (u16*) alloc(512 * 224 * 2); // [W_er ; W_me@W_er] bf16
  u16*   Wl1b = (u16*)  alloc(512 * 256 * 2);
  u16*   Wl2b = (u16*)  alloc(512 * 512 * 2);
  float* cmb  = (float*)alloc(256 * 4);
  u16* Wnr_h = (u16*)alloc(256 * 128 * 2); u16* Wnr_l = (u16*)alloc(256 * 128 * 2);
  u16* Wmh_h = (u16*)alloc(256 * 256 * 2); u16* Wmh_l = (u16*)alloc(256 * 256 * 2);
  u16* Wih_h = (u16*)alloc(768 * 256 * 2); u16* Wih_l = (u16*)alloc(768 * 256 * 2);
  u16* Whh_h = (u16*)alloc(768 * 256 * 2); u16* Whh_l = (u16*)alloc(768 * 256 * 2);
  u16* Wr_h  = (u16*)alloc(117 * 256 * 2); u16* Wr_l  = (u16*)alloc(117 * 256 * 2);

  // single fused prep dispatch (10 jobs via blockIdx.y)
  prep_all_k<<<dim3(1024, 10), 256, 0, stream>>>(
      W_er, Wl1, Wl2, W_nr, W_m, W_ih, W_hh, W_r, b_er, b_m, node,
      Wcomb, Wl1b, Wl2b, Wnr_h, Wnr_l, Wmh_h, Wmh_l,
      Wih_h, Wih_l, Whh_h, Whh_l, Wr_h, Wr_l, node_h, node_l, cmb);

  // es0 (layer-0 e_state) + Em in one pass, edge read once
  fused_front_k<<<2048, dim3(256), 0, stream>>>(edge, Wcomb, b_er, cmb, es0, Em);
  // h0 = node @ W_nr^T + b_nr  (64x64 tiles, 64 blocks)
  gemm_ps64_k<<<dim3(16, 4), dim3(256), 0, stream>>>(
      node_h, node_l, Wnr_h, Wnr_l, b_nr, hbuf, h_h, h_l, 256, 128, 128, 256);

  u16* esbuf[2] = { es0, es1 };
  for (int p = 0; p < 3; ++p) {
    // Hm = h @ W_mh^T and gh = h @ W_hh^T + b_hh — 64x64 tiles, 256 blocks
    gemm_hm_gh_k<<<dim3(16, 16), dim3(256), 0, stream>>>(
        h_h, h_l, Wmh_h, Wmh_l, Whh_h, Whh_l, b_hh, Hm, gh);
    // fused link MLP + message + aggregation (tail writes msum pre-split)
    linkmsg_k<<<1024, dim3(512), 0, stream>>>(
        esbuf[p & 1], Wl1b, bl1, Wl2b, bl2, Wl3, bl3,
        Em, Hm, out_adj, esbuf[(p + 1) & 1], ms_h, ms_l,
        (p == 2) ? 1 : 0, (p < 2) ? 1 : 0);
    // fused GRU input-gate GEMM + GRU update — 64x32 tiles, 128 blocks
    gemm_gru_k<<<dim3(16, 8), dim3(256), 0, stream>>>(
        ms_h, ms_l, Wih_h, Wih_l, b_ih, gh, hbuf, h_h, h_l);
  }
  // labels = h @ W_r^T + b_r  (64x64 tiles, 32 blocks, col-bounds at N=117)
  gemm_ps64_k<<<dim3(16, 2), dim3(256), 0, stream>>>(
      h_h, h_l, Wr_h, Wr_l, b_r, out_lab, nullptr, nullptr, 117, 256, 256, 117);
}